// Round 12
// baseline (534.821 us; speedup 1.0000x reference)
//
#include <hip/hip_runtime.h>
#include <hip/hip_bf16.h>
#include <math.h>

// Problem constants
constexpr int Bb   = 2;
constexpr int S    = 2048;
constexpr int D    = 1024;
constexpr int H    = 16;
constexpr int Dh   = 64;
constexpr int HALF = 32;            // Dh/2
constexpr int M    = Bb * S;        // 4096 rows in the projection GEMMs
constexpr int K    = 1024;
constexpr int N    = 1024;

typedef __attribute__((ext_vector_type(8))) short short8;   // 8 bf16 (4 VGPRs)
typedef __attribute__((ext_vector_type(4))) float f32x4;    // MFMA C/D

// float -> bf16 bits, round-to-nearest-even
__device__ __forceinline__ unsigned short f2bf(float f) {
    unsigned int u = __float_as_uint(f);
    unsigned int r = (u + 0x7fffu + ((u >> 16) & 1u)) >> 16;
    return (unsigned short)r;
}

// async global->LDS, 16B per lane; LDS dest = wave-uniform base + lane*16
__device__ __forceinline__ void gl_lds16(const unsigned short* g, unsigned short* lds_base) {
    __builtin_amdgcn_global_load_lds(
        (const __attribute__((address_space(1))) unsigned int*)g,
        (__attribute__((address_space(3))) unsigned int*)lds_base, 16, 0, 0);
}

// ---------------------------------------------------------------------------
// Fused prep: blocks [0,256) rope tables (double precision),
// [256,4352) x fp32->bf16, [4352,5376) W fp32 [k][n] -> bf16 W^T [n][k],
// [5376] zero the split-K combine flags (re-zeroed every graph replay).
// ---------------------------------------------------------------------------
__global__ __launch_bounds__(256) void prep_kernel(
    const float* __restrict__ x,
    const float* W0, const float* W1, const float* W2, const float* W3,
    unsigned short* __restrict__ xb,
    unsigned short* T0, unsigned short* T1, unsigned short* T2, unsigned short* T3,
    float* __restrict__ cosT, float* __restrict__ sinT,
    unsigned int* __restrict__ flags)
{
    __shared__ float tile[64][65];
    const int bid = blockIdx.x;
    const int tid = threadIdx.x;

    if (bid == 5376) {                        // zero 512 combine flags
        flags[tid] = 0u;
        flags[tid + 256] = 0u;
        return;
    }
    if (bid < 256) {
        int idx = bid * 256 + tid;            // S*HALF = 65536
        int s = idx >> 5;
        int i = idx & 31;
        double freq = exp(-(double)i * (log(10000.0) / 32.0));
        double ang  = (double)s * freq;
        cosT[idx] = (float)cos(ang);
        sinT[idx] = (float)sin(ang);
    } else if (bid < 256 + 4096) {
        size_t i = (size_t)(bid - 256) * 256 + tid;   // over M*K/4
        float4 v = *(const float4*)(x + i * 4);
        ushort4 pk;
        pk.x = f2bf(v.x); pk.y = f2bf(v.y); pk.z = f2bf(v.z); pk.w = f2bf(v.w);
        *(ushort4*)(xb + i * 4) = pk;
    } else {
        int wb = bid - 4352;
        int z  = wb >> 8;
        int rem = wb & 255;
        const float* W = (z == 0) ? W0 : (z == 1) ? W1 : (z == 2) ? W2 : W3;
        unsigned short* T = (z == 0) ? T0 : (z == 1) ? T1 : (z == 2) ? T2 : T3;
        const int bk = (rem >> 4) * 64;   // src row block (k)
        const int bn = (rem & 15) * 64;   // src col block (n)
        const int lr = tid >> 4;          // 0..15
        const int lc = (tid & 15) * 4;    // float4 col

        #pragma unroll
        for (int i = 0; i < 4; ++i) {
            int r = lr + i * 16;
            float4 v = *(const float4*)(W + (size_t)(bk + r) * N + bn + lc);
            tile[r][lc + 0] = v.x; tile[r][lc + 1] = v.y;
            tile[r][lc + 2] = v.z; tile[r][lc + 3] = v.w;
        }
        __syncthreads();
        #pragma unroll
        for (int i = 0; i < 4; ++i) {
            int nr = lr + i * 16;
            ushort4 pk;
            pk.x = f2bf(tile[lc + 0][nr]);
            pk.y = f2bf(tile[lc + 1][nr]);
            pk.z = f2bf(tile[lc + 2][nr]);
            pk.w = f2bf(tile[lc + 3][nr]);
            *(ushort4*)(T + (size_t)(bn + nr) * K + bk + lc) = pk;
        }
    }
}

// ---------------------------------------------------------------------------
// QKV bf16 MFMA GEMM v6 (unchanged): BM=256 x BN=192, BK=64, 4-phase
// counted pipeline, grid (16,16) = 256 blocks = 1/CU.
// ---------------------------------------------------------------------------
__global__ __launch_bounds__(512, 2) void gemm_qkv_kernel(
    const unsigned short* __restrict__ A,
    const unsigned short* __restrict__ BT,
    unsigned short* outQ, unsigned short* outK, unsigned short* outV,
    const float* __restrict__ cosT, const float* __restrict__ sinT)
{
    constexpr int NT    = 16;           // K / 64 k-tiles
    constexpr int ASLOT = 256 * 64;     // shorts per A slot (32 KB)
    constexpr int BSLOT = 192 * 64;     // shorts per B slot (24 KB)
    __shared__ __align__(16) unsigned short As[2 * ASLOT];   // 64 KB
    __shared__ __align__(16) unsigned short Bs[2 * BSLOT];   // 48 KB

    const int tid  = threadIdx.x;
    const int wid  = tid >> 6;
    const int lane = tid & 63;
    const int col  = lane & 15;
    const int quad = lane >> 4;
    const int wr   = wid >> 2;        // m-half owner (0..1), 128 rows
    const int wc   = wid & 3;         // n-quarter owner (0..3), 48 cols

    const int mbase = blockIdx.y * 256;
    const int nbase = blockIdx.x * 192;

    const int srow8 = lane >> 3;      // 0..7
    const int sch8  = lane & 7;       // 16B chunk
    const unsigned short *pA[4], *pB[3];
    unsigned short *dA[4], *dB[3];
    #pragma unroll
    for (int w = 0; w < 4; ++w) {
        int r = wid * 32 + w * 8 + srow8;
        pA[w] = A + (size_t)(mbase + r) * K + ((sch8 + (r >> 1)) & 7) * 8;
        dA[w] = &As[(wid * 32 + w * 8) * 64];
    }
    #pragma unroll
    for (int w = 0; w < 3; ++w) {
        int r = wid * 24 + w * 8 + srow8;
        pB[w] = BT + (size_t)(nbase + r) * K + ((sch8 + (r >> 1)) & 7) * 8;
        dB[w] = &Bs[(wid * 24 + w * 8) * 64];
    }

    int aoff[2][8], boff[2][3];
    #pragma unroll
    for (int kh = 0; kh < 2; ++kh) {
        #pragma unroll
        for (int f = 0; f < 8; ++f) {
            int r = wr * 128 + f * 16 + col;
            aoff[kh][f] = r * 64 + (((kh * 4 + quad) - (r >> 1)) & 7) * 8;
        }
        #pragma unroll
        for (int n = 0; n < 3; ++n) {
            int r = wc * 48 + n * 16 + col;
            boff[kh][n] = r * 64 + (((kh * 4 + quad) - (r >> 1)) & 7) * 8;
        }
    }

    f32x4 acc[8][3];
    #pragma unroll
    for (int f = 0; f < 8; ++f)
        #pragma unroll
        for (int n = 0; n < 3; ++n) acc[f][n] = (f32x4)0.f;

    auto stageA = [&](int slot) {       // 4 instrs
        #pragma unroll
        for (int w = 0; w < 4; ++w) { gl_lds16(pA[w], dA[w] + slot * ASLOT); pA[w] += 64; }
    };
    auto stageB = [&](int slot) {       // 3 instrs
        #pragma unroll
        for (int w = 0; w < 3; ++w) { gl_lds16(pB[w], dB[w] + slot * BSLOT); pB[w] += 64; }
    };

    stageA(0); stageB(0);
    asm volatile("s_waitcnt vmcnt(0)" ::: "memory");
    __builtin_amdgcn_s_barrier();
    __builtin_amdgcn_sched_barrier(0);

    #pragma unroll 1
    for (int t = 0; t < NT; ++t) {
        const unsigned short* Ab = &As[(t & 1) * ASLOT];
        const unsigned short* Bc = &Bs[(t & 1) * BSLOT];
        const int ns = (t + 1) & 1;
        short8 af[4], bf[3];

        // ---- P0: m0-3 x n0-2, kh0; stage A of t+1 ----
        #pragma unroll
        for (int i = 0; i < 4; ++i) af[i] = *(const short8*)&Ab[aoff[0][i]];
        #pragma unroll
        for (int n = 0; n < 3; ++n) bf[n] = *(const short8*)&Bc[boff[0][n]];
        if (t < NT - 1) stageA(ns);
        __builtin_amdgcn_sched_barrier(0);
        __builtin_amdgcn_s_barrier();
        asm volatile("s_waitcnt lgkmcnt(0)" ::: "memory");
        __builtin_amdgcn_s_setprio(1);
        #pragma unroll
        for (int i = 0; i < 4; ++i)
            #pragma unroll
            for (int n = 0; n < 3; ++n)
                acc[i][n] = __builtin_amdgcn_mfma_f32_16x16x32_bf16(af[i], bf[n], acc[i][n], 0, 0, 0);
        __builtin_amdgcn_s_setprio(0);
        __builtin_amdgcn_sched_barrier(0);
        __builtin_amdgcn_s_barrier();
        __builtin_amdgcn_sched_barrier(0);

        // ---- P1: m4-7 x n0-2, kh0 (B reg-cached); stage B of t+1 ----
        #pragma unroll
        for (int i = 0; i < 4; ++i) af[i] = *(const short8*)&Ab[aoff[0][4 + i]];
        if (t < NT - 1) stageB(ns);
        __builtin_amdgcn_sched_barrier(0);
        __builtin_amdgcn_s_barrier();
        asm volatile("s_waitcnt lgkmcnt(0)" ::: "memory");
        __builtin_amdgcn_s_setprio(1);
        #pragma unroll
        for (int i = 0; i < 4; ++i)
            #pragma unroll
            for (int n = 0; n < 3; ++n)
                acc[4 + i][n] = __builtin_amdgcn_mfma_f32_16x16x32_bf16(af[i], bf[n], acc[4 + i][n], 0, 0, 0);
        __builtin_amdgcn_s_setprio(0);
        __builtin_amdgcn_sched_barrier(0);
        __builtin_amdgcn_s_barrier();
        __builtin_amdgcn_sched_barrier(0);

        // ---- P2: m0-3 x n0-2, kh1 ----
        #pragma unroll
        for (int i = 0; i < 4; ++i) af[i] = *(const short8*)&Ab[aoff[1][i]];
        #pragma unroll
        for (int n = 0; n < 3; ++n) bf[n] = *(const short8*)&Bc[boff[1][n]];
        __builtin_amdgcn_sched_barrier(0);
        __builtin_amdgcn_s_barrier();
        asm volatile("s_waitcnt lgkmcnt(0)" ::: "memory");
        __builtin_amdgcn_s_setprio(1);
        #pragma unroll
        for (int i = 0; i < 4; ++i)
            #pragma unroll
            for (int n = 0; n < 3; ++n)
                acc[i][n] = __builtin_amdgcn_mfma_f32_16x16x32_bf16(af[i], bf[n], acc[i][n], 0, 0, 0);
        __builtin_amdgcn_s_setprio(0);
        __builtin_amdgcn_sched_barrier(0);
        __builtin_amdgcn_s_barrier();
        __builtin_amdgcn_sched_barrier(0);

        // ---- P3: m4-7 x n0-2, kh1; drain staging before releasing t+1 ----
        #pragma unroll
        for (int i = 0; i < 4; ++i) af[i] = *(const short8*)&Ab[aoff[1][4 + i]];
        __builtin_amdgcn_sched_barrier(0);
        __builtin_amdgcn_s_barrier();
        asm volatile("s_waitcnt lgkmcnt(0)" ::: "memory");
        __builtin_amdgcn_s_setprio(1);
        #pragma unroll
        for (int i = 0; i < 4; ++i)
            #pragma unroll
            for (int n = 0; n < 3; ++n)
                acc[4 + i][n] = __builtin_amdgcn_mfma_f32_16x16x32_bf16(af[i], bf[n], acc[4 + i][n], 0, 0, 0);
        __builtin_amdgcn_s_setprio(0);
        if (t < NT - 1) { asm volatile("s_waitcnt vmcnt(0)" ::: "memory"); }
        __builtin_amdgcn_sched_barrier(0);
        __builtin_amdgcn_s_barrier();
        __builtin_amdgcn_sched_barrier(0);
    }

    // ---- epilogue: z resolved PER-NI (192-wide tile straddles Q|K|V) ----
    #pragma unroll
    for (int n = 0; n < 3; ++n) {
        int n_g = nbase + wc * 48 + n * 16 + col;   // global stacked-n
        int z   = n_g >> 10;                        // 0:Q 1:K 2:V
        int nl  = n_g & 1023;
        int h = nl >> 6, dh0 = nl & 63;
        if (z < 2) {
            unsigned short* o = z ? outK : outQ;
            int p = dh0 >> 1;
            bool even = !(dh0 & 1);
            #pragma unroll
            for (int f = 0; f < 8; ++f)
                #pragma unroll
                for (int reg = 0; reg < 4; ++reg) {
                    int m_g = mbase + wr * 128 + f * 16 + quad * 4 + reg;
                    int b = m_g >> 11, s = m_g & 2047;
                    float v = acc[f][n][reg];
                    float part = __shfl_xor(v, 1, 64);
                    float c = cosT[s * HALF + p], sn = sinT[s * HALF + p];
                    float r = even ? (v * c - part * sn) : (v * c + part * sn);
                    o[((size_t)(b * H + h) * S + s) * Dh + dh0] = f2bf(r);
                }
        } else {
            #pragma unroll
            for (int f = 0; f < 8; ++f) {
                int m0 = mbase + wr * 128 + f * 16 + quad * 4;
                int b = m0 >> 11, s = m0 & 2047;
                ushort4 pk;
                pk.x = f2bf(acc[f][n][0]);
                pk.y = f2bf(acc[f][n][1]);
                pk.z = f2bf(acc[f][n][2]);
                pk.w = f2bf(acc[f][n][3]);
                *(ushort4*)&outV[((size_t)(b * H + h) * Dh + dh0) * S + s] = pk;
            }
        }
    }
}

// ---------------------------------------------------------------------------
// Out-projection bf16 MFMA GEMM v2 (unchanged): 64x64 tiles, BK=64,
// grid (16,64) = 1024 blocks -> 4 blocks/CU. Waves 2x2. fp32 out + bias.
// ---------------------------------------------------------------------------
__global__ __launch_bounds__(256) void gemm_out_kernel(
    const unsigned short* __restrict__ A,
    const unsigned short* __restrict__ BT,
    float* __restrict__ outO, const float* __restrict__ bias)
{
    constexpr int BK   = 64;
    constexpr int ABUF = 64 * BK;     // 8 KB
    constexpr int BBUF = 64 * BK;     // 8 KB
    __shared__ __align__(16) unsigned short As[2 * ABUF];
    __shared__ __align__(16) unsigned short Bs[2 * BBUF];

    const int tid  = threadIdx.x;
    const int wave = tid >> 6;
    const int lane = tid & 63;
    const int col  = lane & 15;
    const int quad = lane >> 4;
    const int wy   = wave >> 1;
    const int wx   = wave & 1;

    const int mbase = blockIdx.y * 64;
    const int nbase = blockIdx.x * 64;

    const int srow8 = lane >> 3;      // 8 rows per gl_lds16 (row = 128B)
    const int sch8  = lane & 7;

    const unsigned short *pA[2], *pB[2];
    unsigned short *dA[2], *dB[2];
    #pragma unroll
    for (int w = 0; w < 2; ++w) {
        int base = wave * 16 + w * 8;
        int tr = base + srow8;
        pA[w] = A  + (size_t)(mbase + tr) * K + ((sch8 + (tr >> 1)) & 7) * 8;
        pB[w] = BT + (size_t)(nbase + tr) * K + ((sch8 + (tr >> 1)) & 7) * 8;
        dA[w] = &As[base * BK];
        dB[w] = &Bs[base * BK];
    }

    int aoff[2][2], boff[2][2];
    #pragma unroll
    for (int ks = 0; ks < 2; ++ks) {
        #pragma unroll
        for (int mi = 0; mi < 2; ++mi) {
            int r = wy * 32 + mi * 16 + col;
            aoff[ks][mi] = r * BK + (((ks * 4 + quad) - (r >> 1)) & 7) * 8;
        }
        #pragma unroll
        for (int ni = 0; ni < 2; ++ni) {
            int r = wx * 32 + ni * 16 + col;
            boff[ks][ni] = r * BK + (((ks * 4 + quad) - (r >> 1)) & 7) * 8;
        }
    }

    f32x4 acc[2][2];
    #pragma unroll
    for (int mi = 0; mi < 2; ++mi)
        #pragma unroll
        for (int ni = 0; ni < 2; ++ni) acc[mi][ni] = (f32x4)0.f;

    auto stage = [&](int buf) {
        #pragma unroll
        for (int w = 0; w < 2; ++w) { gl_lds16(pA[w], dA[w] + buf * ABUF); pA[w] += BK; }
        #pragma unroll
        for (int w = 0; w < 2; ++w) { gl_lds16(pB[w], dB[w] + buf * BBUF); pB[w] += BK; }
    };
    auto compute = [&](int buf) {
        const unsigned short* Ac = &As[buf * ABUF];
        const unsigned short* Bc = &Bs[buf * BBUF];
        #pragma unroll
        for (int ks = 0; ks < 2; ++ks) {
            short8 af[2], bfr[2];
            #pragma unroll
            for (int mi = 0; mi < 2; ++mi) af[mi] = *(const short8*)&Ac[aoff[ks][mi]];
            #pragma unroll
            for (int ni = 0; ni < 2; ++ni) bfr[ni] = *(const short8*)&Bc[boff[ks][ni]];
            #pragma unroll
            for (int mi = 0; mi < 2; ++mi)
                #pragma unroll
                for (int ni = 0; ni < 2; ++ni)
                    acc[mi][ni] = __builtin_amdgcn_mfma_f32_16x16x32_bf16(af[mi], bfr[ni], acc[mi][ni], 0, 0, 0);
        }
    };

    stage(0);
    #pragma unroll 1
    for (int kk = 0; kk < 16; kk += 2) {
        __syncthreads();
        if (kk + 1 < 16) stage(1);
        compute(0);
        __syncthreads();
        if (kk + 2 < 16) stage(0);
        compute(1);
    }

    #pragma unroll
    for (int ni = 0; ni < 2; ++ni) {
        int n_g = nbase + wx * 32 + ni * 16 + col;
        float bv = bias[n_g];
        #pragma unroll
        for (int mi = 0; mi < 2; ++mi)
            #pragma unroll
            for (int reg = 0; reg < 4; ++reg) {
                int m_g = mbase + wy * 32 + mi * 16 + quad * 4 + reg;
                outO[(size_t)m_g * N + n_g] = acc[mi][ni][reg] + bv;
            }
    }
}

// ---------------------------------------------------------------------------
// MFMA flash attention v12: v11 (QBLK=128, 2-way split-K, XCD-locality
// swizzle) + FUSED COMBINE via last-finisher atomic -- combine_kernel and
// its ~10us launch overhead are deleted. Each block writes fp32 partials,
// threadfence + agent-scope atomicAdd on flags[bh*16+qt]; the SECOND
// arriver re-fences, reads the OTHER parity's partials (own still in
// registers), adds, normalizes, writes bf16 ctx. XCD swizzle puts both
// parities of (bh,qt) on the same XCD in practice (L2-hot cross-read);
// correctness relies only on device-scope atomics/fences (G16).
// ---------------------------------------------------------------------------
__global__ __launch_bounds__(512, 4) void attn_mfma_kernel(
    const unsigned short* __restrict__ q, const unsigned short* __restrict__ k,
    const unsigned short* __restrict__ vt,
    float* __restrict__ Opart, float* __restrict__ lpart,
    unsigned short* __restrict__ ctx, unsigned int* __restrict__ flags)
{
    constexpr int TSZ = 64 * 64;
    __shared__ __align__(16) unsigned short Ks[2 * TSZ];    // 16 KB
    __shared__ __align__(16) unsigned short Vs[2 * TSZ];    // 16 KB
    __shared__ __align__(16) unsigned short Ps[8][16 * 64]; // 16 KB, XOR-swizzled
    __shared__ unsigned int lastflag;

    const int tid  = threadIdx.x;
    const int wave = tid >> 6;        // 0..7
    const int lane = tid & 63;
    const int col  = lane & 15;
    const int quad = lane >> 4;
    const int r8   = lane >> 3, cp = lane & 7;

    // XCD-locality swizzle (v11): all 16 blocks of a bh share lin%8.
    const int lin   = (int)blockIdx.y * 16 + (int)blockIdx.x;
    const int bh    = (lin & 7) + 8 * ((lin >> 3) & 3);
    const int pairh = lin >> 5;       // 0..15
    const int pair  = pairh >> 1;     // 0..7
    const int hpar  = pairh & 1;      // key-tile parity this block owns

    const unsigned short* qb = q  + (size_t)bh * S * Dh;
    const unsigned short* kb = k  + (size_t)bh * S * Dh;
    const unsigned short* vb = vt + (size_t)bh * Dh * S;

    unsigned short* dk = &Ks[(wave * 8) * 64];
    unsigned short* dv = &Vs[(wave * 8) * 64];

    int foff[2][4];                   // K/V fragment reads, rot = local row
    #pragma unroll
    for (int ks = 0; ks < 2; ++ks)
        #pragma unroll
        for (int nt = 0; nt < 4; ++nt) {
            int r = nt * 16 + col;
            foff[ks][nt] = r * 64 + (((ks * 4 + quad) - r) & 7) * 8;
        }
    // Ps layout [row=16][key=64] shorts, 16B-chunk XOR swizzle: chunk ^= row&7
    int poffW[4][4];
    #pragma unroll
    for (int nt = 0; nt < 4; ++nt)
        #pragma unroll
        for (int reg = 0; reg < 4; ++reg) {
            int row = quad * 4 + reg;
            poffW[nt][reg] = row * 64 + (((nt * 2 + (col >> 3)) ^ (row & 7)) << 3) + (col & 7);
        }
    int poffR[2];
    #pragma unroll
    for (int ks = 0; ks < 2; ++ks)
        poffR[ks] = col * 64 + (((ks * 4 + quad) ^ (col & 7)) << 3);

    for (int phase = 0; phase < 2; ++phase) {
        const int qt  = phase ? (15 - pair) : pair;     // 128-row q-tile
        const int wr0 = qt * 128 + wave * 16;           // wave's first q-row
        const int NV  = qt + 1;                         // visits this phase

        // staging pointers: local row r within 64-row tile; first tile = hpar
        const unsigned short *pk, *pv;
        {
            int r = wave * 8 + r8;
            pk = kb + (size_t)(hpar * 64 + r) * Dh + ((cp + r) & 7) * 8;
            pv = vb + (size_t)r * S + hpar * 64 + ((cp + r) & 7) * 8;
        }
        auto stageKV = [&](int buf) {      // stage current tile, advance 2 tiles
            gl_lds16(pk, dk + buf * TSZ);
            gl_lds16(pv, dv + buf * TSZ);
            pk += 128 * Dh;
            pv += 128;
        };

        __syncthreads();                   // protect buffers from prev phase
        stageKV(0);

        short8 qfrag[2];
        #pragma unroll
        for (int ks = 0; ks < 2; ++ks)
            qfrag[ks] = *(const short8*)(qb + (size_t)(wr0 + col) * Dh + ks * 32 + quad * 8);

        f32x4 O[4];
        float lacc[4];
        #pragma unroll
        for (int nt = 0; nt < 4; ++nt) O[nt] = (f32x4)0.f;
        #pragma unroll
        for (int r = 0; r < 4; ++r) lacc[r] = 0.f;

        auto subtile = [&](const unsigned short* Kc, const unsigned short* Vc, int t) {
            f32x4 sacc[4];
            #pragma unroll
            for (int nt = 0; nt < 4; ++nt) sacc[nt] = (f32x4)0.f;
            #pragma unroll
            for (int ks = 0; ks < 2; ++ks)
                #pragma unroll
                for (int nt = 0; nt < 4; ++nt) {
                    short8 kf = *(const short8*)&Kc[foff[ks][nt]];
                    sacc[nt] = __builtin_amdgcn_mfma_f32_16x16x32_bf16(qfrag[ks], kf, sacc[nt], 0, 0, 0);
                }
            const bool edge = (t * 64 + 63 > wr0);   // tile may exceed q-rows
            float pb[4][4];
            #pragma unroll
            for (int nt = 0; nt < 4; ++nt) {
                int key_g = t * 64 + nt * 16 + col;
                #pragma unroll
                for (int reg = 0; reg < 4; ++reg) {
                    // exp(s/8 - 8) = exp2(s * 0.125*log2e - 8*log2e)
                    float e = __builtin_amdgcn_exp2f(
                        fmaf(sacc[nt][reg], 0.18033688011112042f, -11.541560327111707f));
                    if (edge && key_g > wr0 + quad * 4 + reg) e = 0.f;
                    pb[nt][reg] = e;
                }
            }
            #pragma unroll
            for (int reg = 0; reg < 4; ++reg)
                lacc[reg] += (pb[0][reg] + pb[1][reg]) + (pb[2][reg] + pb[3][reg]);
            #pragma unroll
            for (int nt = 0; nt < 4; ++nt)
                #pragma unroll
                for (int reg = 0; reg < 4; ++reg)
                    Ps[wave][poffW[nt][reg]] = f2bf(pb[nt][reg]);
            #pragma unroll
            for (int ks = 0; ks < 2; ++ks) {
                short8 pf = *(const short8*)&Ps[wave][poffR[ks]];
                #pragma unroll
                for (int nt = 0; nt < 4; ++nt) {
                    short8 vf = *(const short8*)&Vc[foff[ks][nt]];
                    O[nt] = __builtin_amdgcn_mfma_f32_16x16x32_bf16(pf, vf, O[nt], 0, 0, 0);
                }
            }
        };

        for (int j = 0; j < NV; ++j) {
            __syncthreads();               // drains prefetch of visit j
            if (j + 1 < NV) stageKV((j + 1) & 1);
            const int t = hpar + 2 * j;    // global 64-key tile index
            if (t * 64 <= wr0 + 15)        // skip fully-masked tiles
                subtile(&Ks[(j & 1) * TSZ], &Vs[(j & 1) * TSZ], t);
        }

        #pragma unroll
        for (int reg = 0; reg < 4; ++reg) {
            float s = lacc[reg];
            #pragma unroll
            for (int off = 1; off <= 8; off <<= 1)
                s += __shfl_xor(s, off, 64);
            lacc[reg] = s;
        }

        // write unnormalized fp32 partials
        const size_t pb_base = (size_t)(hpar * 32 + bh) * S;
        #pragma unroll
        for (int reg = 0; reg < 4; ++reg) {
            int rg = wr0 + quad * 4 + reg;
            float* op = Opart + (pb_base + rg) * 64 + col;
            #pragma unroll
            for (int nt = 0; nt < 4; ++nt)
                op[nt * 16] = O[nt][reg];
            if (col == 0)
                lpart[pb_base + rg] = lacc[reg];
        }

        // ---- fused combine: last finisher of (bh,qt) merges parities ----
        __threadfence();                   // release own partial writes
        __syncthreads();                   // all threads' fences precede atomic
        if (tid == 0)
            lastflag = __hip_atomic_fetch_add(&flags[bh * 16 + qt], 1u,
                                              __ATOMIC_ACQ_REL,
                                              __HIP_MEMORY_SCOPE_AGENT);
        __syncthreads();
        if (lastflag == 1u) {              // we are second: combine + write ctx
            __threadfence();               // acquire other parity's writes
            const size_t ob = (size_t)((1 - hpar) * 32 + bh) * S;
            const int b = bh >> 4, hh = bh & 15;
            #pragma unroll
            for (int reg = 0; reg < 4; ++reg) {
                int rg = wr0 + quad * 4 + reg;
                const float* op = Opart + (ob + rg) * 64 + col;
                float linv = 1.0f / (lacc[reg] + lpart[ob + rg]);
                unsigned short* dst = ctx + ((size_t)b * S + rg) * 1024 + hh * 64 + col;
                #pragma unroll
                for (int nt = 0; nt < 4; ++nt)
                    dst[nt * 16] = f2bf((O[nt][reg] + op[nt * 16]) * linv);
            }
        }
    }
}

// ---------------------------------------------------------------------------
extern "C" void kernel_launch(void* const* d_in, const int* in_sizes, int n_in,
                              void* d_out, int out_size, void* d_ws, size_t ws_size,
                              hipStream_t stream) {
    const float* x  = (const float*)d_in[0];
    const float* Wq = (const float*)d_in[1];
    const float* Wk = (const float*)d_in[2];
    const float* Wv = (const float*)d_in[3];
    const float* Wo = (const float*)d_in[4];
    const float* bo = (const float*)d_in[5];
    float* out = (float*)d_out;

    const size_t MK  = (size_t)M * K;        // 4M
    const size_t NK  = (size_t)N * K;        // 1M
    const size_t QKV = (size_t)Bb * H * S * Dh;

    unsigned short* xb   = (unsigned short*)d_ws;
    unsigned short* WqT  = xb  + MK;         // WqT/WkT/WvT contiguous = stacked [3072][1024]
    unsigned short* WkT  = WqT + NK;
    unsigned short* WvT  = WkT + NK;
    unsigned short* WoT  = WvT + NK;
    unsigned short* qbuf = WoT + NK;
    unsigned short* kbuf = qbuf + QKV;
    unsigned short* vtb  = kbuf + QKV;
    unsigned short* ctxb = vtb  + QKV;
    float* cosT  = (float*)(ctxb + QKV);
    float* sinT  = cosT + (size_t)S * HALF;
    float* Opart = sinT + (size_t)S * HALF;               // 2*32*2048*64 fp32
    float* lpart = Opart + (size_t)2 * 32 * S * 64;       // 2*32*2048 fp32
    unsigned int* flags = (unsigned int*)(lpart + (size_t)2 * 32 * S);  // 512

    // fused prep: rope tables + x->bf16 + 4x W transpose->bf16 + flag zero
    prep_kernel<<<5377, 256, 0, stream>>>(x, Wq, Wk, Wv, Wo,
                                          xb, WqT, WkT, WvT, WoT, cosT, sinT,
                                          flags);

    // fused QKV projections as one stacked-N GEMM (+RoPE, +V transpose)
    gemm_qkv_kernel<<<dim3(16, 16), 512, 0, stream>>>(
        xb, WqT, qbuf, kbuf, vtb, cosT, sinT);

    // flash attention v12: split-K with FUSED last-finisher combine
    attn_mfma_kernel<<<dim3(16, Bb * H), 512, 0, stream>>>(
        qbuf, kbuf, vtb, Opart, lpart, ctxb, flags);

    // output projection: 64x64 tiles, BK=64, 1024 blocks = 4/CU
    gemm_out_kernel<<<dim3(16, 64), 256, 0, stream>>>(ctxb, WoT, out, bo);
}

// Round 13
// 186.314 us; speedup vs baseline: 2.8705x; 2.8705x over previous
//
#include <hip/hip_runtime.h>
#include <hip/hip_bf16.h>
#include <math.h>

// Problem constants
constexpr int Bb   = 2;
constexpr int S    = 2048;
constexpr int D    = 1024;
constexpr int H    = 16;
constexpr int Dh   = 64;
constexpr int HALF = 32;            // Dh/2
constexpr int M    = Bb * S;        // 4096 rows in the projection GEMMs
constexpr int K    = 1024;
constexpr int N    = 1024;

typedef __attribute__((ext_vector_type(8))) short short8;   // 8 bf16 (4 VGPRs)
typedef __attribute__((ext_vector_type(4))) float f32x4;    // MFMA C/D

// float -> bf16 bits, round-to-nearest-even
__device__ __forceinline__ unsigned short f2bf(float f) {
    unsigned int u = __float_as_uint(f);
    unsigned int r = (u + 0x7fffu + ((u >> 16) & 1u)) >> 16;
    return (unsigned short)r;
}

// async global->LDS, 16B per lane; LDS dest = wave-uniform base + lane*16
__device__ __forceinline__ void gl_lds16(const unsigned short* g, unsigned short* lds_base) {
    __builtin_amdgcn_global_load_lds(
        (const __attribute__((address_space(1))) unsigned int*)g,
        (__attribute__((address_space(3))) unsigned int*)lds_base, 16, 0, 0);
}

// ---------------------------------------------------------------------------
// Fused prep: blocks [0,256) rope tables (double precision),
// [256,4352) x fp32->bf16, [4352,5376) W fp32 [k][n] -> bf16 W^T [n][k].
// ---------------------------------------------------------------------------
__global__ __launch_bounds__(256) void prep_kernel(
    const float* __restrict__ x,
    const float* W0, const float* W1, const float* W2, const float* W3,
    unsigned short* __restrict__ xb,
    unsigned short* T0, unsigned short* T1, unsigned short* T2, unsigned short* T3,
    float* __restrict__ cosT, float* __restrict__ sinT)
{
    __shared__ float tile[64][65];
    const int bid = blockIdx.x;
    const int tid = threadIdx.x;

    if (bid < 256) {
        int idx = bid * 256 + tid;            // S*HALF = 65536
        int s = idx >> 5;
        int i = idx & 31;
        double freq = exp(-(double)i * (log(10000.0) / 32.0));
        double ang  = (double)s * freq;
        cosT[idx] = (float)cos(ang);
        sinT[idx] = (float)sin(ang);
    } else if (bid < 256 + 4096) {
        size_t i = (size_t)(bid - 256) * 256 + tid;   // over M*K/4
        float4 v = *(const float4*)(x + i * 4);
        ushort4 pk;
        pk.x = f2bf(v.x); pk.y = f2bf(v.y); pk.z = f2bf(v.z); pk.w = f2bf(v.w);
        *(ushort4*)(xb + i * 4) = pk;
    } else {
        int wb = bid - 4352;
        int z  = wb >> 8;
        int rem = wb & 255;
        const float* W = (z == 0) ? W0 : (z == 1) ? W1 : (z == 2) ? W2 : W3;
        unsigned short* T = (z == 0) ? T0 : (z == 1) ? T1 : (z == 2) ? T2 : T3;
        const int bk = (rem >> 4) * 64;   // src row block (k)
        const int bn = (rem & 15) * 64;   // src col block (n)
        const int lr = tid >> 4;          // 0..15
        const int lc = (tid & 15) * 4;    // float4 col

        #pragma unroll
        for (int i = 0; i < 4; ++i) {
            int r = lr + i * 16;
            float4 v = *(const float4*)(W + (size_t)(bk + r) * N + bn + lc);
            tile[r][lc + 0] = v.x; tile[r][lc + 1] = v.y;
            tile[r][lc + 2] = v.z; tile[r][lc + 3] = v.w;
        }
        __syncthreads();
        #pragma unroll
        for (int i = 0; i < 4; ++i) {
            int nr = lr + i * 16;
            ushort4 pk;
            pk.x = f2bf(tile[lc + 0][nr]);
            pk.y = f2bf(tile[lc + 1][nr]);
            pk.z = f2bf(tile[lc + 2][nr]);
            pk.w = f2bf(tile[lc + 3][nr]);
            *(ushort4*)(T + (size_t)(bn + nr) * K + bk + lc) = pk;
        }
    }
}

// ---------------------------------------------------------------------------
// QKV bf16 MFMA GEMM v6b: v6 with bank-conflict FIX. BK=64 rows are 128B
// = exactly 32 banks, so row*64 contributes no bank bits; v6's rot=r>>1
// left adjacent-row lanes on identical bank quads -> 2.88M conflict cyc
// measured (r11). attn uses rot=r on the SAME 128B-row geometry and
// measures 0 conflicts -> switch staging source offset AND read offsets
// to rot=r (same involution). Everything else unchanged.
// ---------------------------------------------------------------------------
__global__ __launch_bounds__(512, 2) void gemm_qkv_kernel(
    const unsigned short* __restrict__ A,
    const unsigned short* __restrict__ BT,
    unsigned short* outQ, unsigned short* outK, unsigned short* outV,
    const float* __restrict__ cosT, const float* __restrict__ sinT)
{
    constexpr int NT    = 16;           // K / 64 k-tiles
    constexpr int ASLOT = 256 * 64;     // shorts per A slot (32 KB)
    constexpr int BSLOT = 192 * 64;     // shorts per B slot (24 KB)
    __shared__ __align__(16) unsigned short As[2 * ASLOT];   // 64 KB
    __shared__ __align__(16) unsigned short Bs[2 * BSLOT];   // 48 KB

    const int tid  = threadIdx.x;
    const int wid  = tid >> 6;
    const int lane = tid & 63;
    const int col  = lane & 15;
    const int quad = lane >> 4;
    const int wr   = wid >> 2;        // m-half owner (0..1), 128 rows
    const int wc   = wid & 3;         // n-quarter owner (0..3), 48 cols

    const int mbase = blockIdx.y * 256;
    const int nbase = blockIdx.x * 192;

    const int srow8 = lane >> 3;      // 0..7
    const int sch8  = lane & 7;       // 16B chunk
    const unsigned short *pA[4], *pB[3];
    unsigned short *dA[4], *dB[3];
    #pragma unroll
    for (int w = 0; w < 4; ++w) {
        int r = wid * 32 + w * 8 + srow8;
        pA[w] = A + (size_t)(mbase + r) * K + ((sch8 + r) & 7) * 8;   // rot=r
        dA[w] = &As[(wid * 32 + w * 8) * 64];
    }
    #pragma unroll
    for (int w = 0; w < 3; ++w) {
        int r = wid * 24 + w * 8 + srow8;
        pB[w] = BT + (size_t)(nbase + r) * K + ((sch8 + r) & 7) * 8;  // rot=r
        dB[w] = &Bs[(wid * 24 + w * 8) * 64];
    }

    int aoff[2][8], boff[2][3];
    #pragma unroll
    for (int kh = 0; kh < 2; ++kh) {
        #pragma unroll
        for (int f = 0; f < 8; ++f) {
            int r = wr * 128 + f * 16 + col;
            aoff[kh][f] = r * 64 + (((kh * 4 + quad) - r) & 7) * 8;   // rot=r
        }
        #pragma unroll
        for (int n = 0; n < 3; ++n) {
            int r = wc * 48 + n * 16 + col;
            boff[kh][n] = r * 64 + (((kh * 4 + quad) - r) & 7) * 8;   // rot=r
        }
    }

    f32x4 acc[8][3];
    #pragma unroll
    for (int f = 0; f < 8; ++f)
        #pragma unroll
        for (int n = 0; n < 3; ++n) acc[f][n] = (f32x4)0.f;

    auto stageA = [&](int slot) {       // 4 instrs
        #pragma unroll
        for (int w = 0; w < 4; ++w) { gl_lds16(pA[w], dA[w] + slot * ASLOT); pA[w] += 64; }
    };
    auto stageB = [&](int slot) {       // 3 instrs
        #pragma unroll
        for (int w = 0; w < 3; ++w) { gl_lds16(pB[w], dB[w] + slot * BSLOT); pB[w] += 64; }
    };

    stageA(0); stageB(0);
    asm volatile("s_waitcnt vmcnt(0)" ::: "memory");
    __builtin_amdgcn_s_barrier();
    __builtin_amdgcn_sched_barrier(0);

    #pragma unroll 1
    for (int t = 0; t < NT; ++t) {
        const unsigned short* Ab = &As[(t & 1) * ASLOT];
        const unsigned short* Bc = &Bs[(t & 1) * BSLOT];
        const int ns = (t + 1) & 1;
        short8 af[4], bf[3];

        // ---- P0: m0-3 x n0-2, kh0; stage A of t+1 ----
        #pragma unroll
        for (int i = 0; i < 4; ++i) af[i] = *(const short8*)&Ab[aoff[0][i]];
        #pragma unroll
        for (int n = 0; n < 3; ++n) bf[n] = *(const short8*)&Bc[boff[0][n]];
        if (t < NT - 1) stageA(ns);
        __builtin_amdgcn_sched_barrier(0);
        __builtin_amdgcn_s_barrier();
        asm volatile("s_waitcnt lgkmcnt(0)" ::: "memory");
        __builtin_amdgcn_s_setprio(1);
        #pragma unroll
        for (int i = 0; i < 4; ++i)
            #pragma unroll
            for (int n = 0; n < 3; ++n)
                acc[i][n] = __builtin_amdgcn_mfma_f32_16x16x32_bf16(af[i], bf[n], acc[i][n], 0, 0, 0);
        __builtin_amdgcn_s_setprio(0);
        __builtin_amdgcn_sched_barrier(0);
        __builtin_amdgcn_s_barrier();
        __builtin_amdgcn_sched_barrier(0);

        // ---- P1: m4-7 x n0-2, kh0 (B reg-cached); stage B of t+1 ----
        #pragma unroll
        for (int i = 0; i < 4; ++i) af[i] = *(const short8*)&Ab[aoff[0][4 + i]];
        if (t < NT - 1) stageB(ns);
        __builtin_amdgcn_sched_barrier(0);
        __builtin_amdgcn_s_barrier();
        asm volatile("s_waitcnt lgkmcnt(0)" ::: "memory");
        __builtin_amdgcn_s_setprio(1);
        #pragma unroll
        for (int i = 0; i < 4; ++i)
            #pragma unroll
            for (int n = 0; n < 3; ++n)
                acc[4 + i][n] = __builtin_amdgcn_mfma_f32_16x16x32_bf16(af[i], bf[n], acc[4 + i][n], 0, 0, 0);
        __builtin_amdgcn_s_setprio(0);
        __builtin_amdgcn_sched_barrier(0);
        __builtin_amdgcn_s_barrier();
        __builtin_amdgcn_sched_barrier(0);

        // ---- P2: m0-3 x n0-2, kh1 ----
        #pragma unroll
        for (int i = 0; i < 4; ++i) af[i] = *(const short8*)&Ab[aoff[1][i]];
        #pragma unroll
        for (int n = 0; n < 3; ++n) bf[n] = *(const short8*)&Bc[boff[1][n]];
        __builtin_amdgcn_sched_barrier(0);
        __builtin_amdgcn_s_barrier();
        asm volatile("s_waitcnt lgkmcnt(0)" ::: "memory");
        __builtin_amdgcn_s_setprio(1);
        #pragma unroll
        for (int i = 0; i < 4; ++i)
            #pragma unroll
            for (int n = 0; n < 3; ++n)
                acc[i][n] = __builtin_amdgcn_mfma_f32_16x16x32_bf16(af[i], bf[n], acc[i][n], 0, 0, 0);
        __builtin_amdgcn_s_setprio(0);
        __builtin_amdgcn_sched_barrier(0);
        __builtin_amdgcn_s_barrier();
        __builtin_amdgcn_sched_barrier(0);

        // ---- P3: m4-7 x n0-2, kh1; drain staging before releasing t+1 ----
        #pragma unroll
        for (int i = 0; i < 4; ++i) af[i] = *(const short8*)&Ab[aoff[1][4 + i]];
        __builtin_amdgcn_sched_barrier(0);
        __builtin_amdgcn_s_barrier();
        asm volatile("s_waitcnt lgkmcnt(0)" ::: "memory");
        __builtin_amdgcn_s_setprio(1);
        #pragma unroll
        for (int i = 0; i < 4; ++i)
            #pragma unroll
            for (int n = 0; n < 3; ++n)
                acc[4 + i][n] = __builtin_amdgcn_mfma_f32_16x16x32_bf16(af[i], bf[n], acc[4 + i][n], 0, 0, 0);
        __builtin_amdgcn_s_setprio(0);
        if (t < NT - 1) { asm volatile("s_waitcnt vmcnt(0)" ::: "memory"); }
        __builtin_amdgcn_sched_barrier(0);
        __builtin_amdgcn_s_barrier();
        __builtin_amdgcn_sched_barrier(0);
    }

    // ---- epilogue: z resolved PER-NI (192-wide tile straddles Q|K|V) ----
    #pragma unroll
    for (int n = 0; n < 3; ++n) {
        int n_g = nbase + wc * 48 + n * 16 + col;   // global stacked-n
        int z   = n_g >> 10;                        // 0:Q 1:K 2:V
        int nl  = n_g & 1023;
        int h = nl >> 6, dh0 = nl & 63;
        if (z < 2) {
            unsigned short* o = z ? outK : outQ;
            int p = dh0 >> 1;
            bool even = !(dh0 & 1);
            #pragma unroll
            for (int f = 0; f < 8; ++f)
                #pragma unroll
                for (int reg = 0; reg < 4; ++reg) {
                    int m_g = mbase + wr * 128 + f * 16 + quad * 4 + reg;
                    int b = m_g >> 11, s = m_g & 2047;
                    float v = acc[f][n][reg];
                    float part = __shfl_xor(v, 1, 64);
                    float c = cosT[s * HALF + p], sn = sinT[s * HALF + p];
                    float r = even ? (v * c - part * sn) : (v * c + part * sn);
                    o[((size_t)(b * H + h) * S + s) * Dh + dh0] = f2bf(r);
                }
        } else {
            #pragma unroll
            for (int f = 0; f < 8; ++f) {
                int m0 = mbase + wr * 128 + f * 16 + quad * 4;
                int b = m0 >> 11, s = m0 & 2047;
                ushort4 pk;
                pk.x = f2bf(acc[f][n][0]);
                pk.y = f2bf(acc[f][n][1]);
                pk.z = f2bf(acc[f][n][2]);
                pk.w = f2bf(acc[f][n][3]);
                *(ushort4*)&outV[((size_t)(b * H + h) * Dh + dh0) * S + s] = pk;
            }
        }
    }
}

// ---------------------------------------------------------------------------
// Out-projection bf16 MFMA GEMM v2b: bank-conflict fix rot=r>>1 -> rot=r
// (same 128B-row geometry as qkv). Otherwise unchanged.
// ---------------------------------------------------------------------------
__global__ __launch_bounds__(256) void gemm_out_kernel(
    const unsigned short* __restrict__ A,
    const unsigned short* __restrict__ BT,
    float* __restrict__ outO, const float* __restrict__ bias)
{
    constexpr int BK   = 64;
    constexpr int ABUF = 64 * BK;     // 8 KB
    constexpr int BBUF = 64 * BK;     // 8 KB
    __shared__ __align__(16) unsigned short As[2 * ABUF];
    __shared__ __align__(16) unsigned short Bs[2 * BBUF];

    const int tid  = threadIdx.x;
    const int wave = tid >> 6;
    const int lane = tid & 63;
    const int col  = lane & 15;
    const int quad = lane >> 4;
    const int wy   = wave >> 1;
    const int wx   = wave & 1;

    const int mbase = blockIdx.y * 64;
    const int nbase = blockIdx.x * 64;

    const int srow8 = lane >> 3;      // 8 rows per gl_lds16 (row = 128B)
    const int sch8  = lane & 7;

    const unsigned short *pA[2], *pB[2];
    unsigned short *dA[2], *dB[2];
    #pragma unroll
    for (int w = 0; w < 2; ++w) {
        int base = wave * 16 + w * 8;
        int tr = base + srow8;
        pA[w] = A  + (size_t)(mbase + tr) * K + ((sch8 + tr) & 7) * 8;   // rot=r
        pB[w] = BT + (size_t)(nbase + tr) * K + ((sch8 + tr) & 7) * 8;   // rot=r
        dA[w] = &As[base * BK];
        dB[w] = &Bs[base * BK];
    }

    int aoff[2][2], boff[2][2];
    #pragma unroll
    for (int ks = 0; ks < 2; ++ks) {
        #pragma unroll
        for (int mi = 0; mi < 2; ++mi) {
            int r = wy * 32 + mi * 16 + col;
            aoff[ks][mi] = r * BK + (((ks * 4 + quad) - r) & 7) * 8;     // rot=r
        }
        #pragma unroll
        for (int ni = 0; ni < 2; ++ni) {
            int r = wx * 32 + ni * 16 + col;
            boff[ks][ni] = r * BK + (((ks * 4 + quad) - r) & 7) * 8;     // rot=r
        }
    }

    f32x4 acc[2][2];
    #pragma unroll
    for (int mi = 0; mi < 2; ++mi)
        #pragma unroll
        for (int ni = 0; ni < 2; ++ni) acc[mi][ni] = (f32x4)0.f;

    auto stage = [&](int buf) {
        #pragma unroll
        for (int w = 0; w < 2; ++w) { gl_lds16(pA[w], dA[w] + buf * ABUF); pA[w] += BK; }
        #pragma unroll
        for (int w = 0; w < 2; ++w) { gl_lds16(pB[w], dB[w] + buf * BBUF); pB[w] += BK; }
    };
    auto compute = [&](int buf) {
        const unsigned short* Ac = &As[buf * ABUF];
        const unsigned short* Bc = &Bs[buf * BBUF];
        #pragma unroll
        for (int ks = 0; ks < 2; ++ks) {
            short8 af[2], bfr[2];
            #pragma unroll
            for (int mi = 0; mi < 2; ++mi) af[mi] = *(const short8*)&Ac[aoff[ks][mi]];
            #pragma unroll
            for (int ni = 0; ni < 2; ++ni) bfr[ni] = *(const short8*)&Bc[boff[ks][ni]];
            #pragma unroll
            for (int mi = 0; mi < 2; ++mi)
                #pragma unroll
                for (int ni = 0; ni < 2; ++ni)
                    acc[mi][ni] = __builtin_amdgcn_mfma_f32_16x16x32_bf16(af[mi], bfr[ni], acc[mi][ni], 0, 0, 0);
        }
    };

    stage(0);
    #pragma unroll 1
    for (int kk = 0; kk < 16; kk += 2) {
        __syncthreads();
        if (kk + 1 < 16) stage(1);
        compute(0);
        __syncthreads();
        if (kk + 2 < 16) stage(0);
        compute(1);
    }

    #pragma unroll
    for (int ni = 0; ni < 2; ++ni) {
        int n_g = nbase + wx * 32 + ni * 16 + col;
        float bv = bias[n_g];
        #pragma unroll
        for (int mi = 0; mi < 2; ++mi)
            #pragma unroll
            for (int reg = 0; reg < 4; ++reg) {
                int m_g = mbase + wy * 32 + mi * 16 + quad * 4 + reg;
                outO[(size_t)m_g * N + n_g] = acc[mi][ni][reg] + bv;
            }
    }
}

// ---------------------------------------------------------------------------
// MFMA flash attention v11 (reverted from v12 -- device-fence fused combine
// serialized L2 writebacks, 9x regression): QBLK=128, 2-way split-K,
// XCD-locality swizzle, fp32 partials + separate combine kernel.
// ---------------------------------------------------------------------------
__global__ __launch_bounds__(512, 4) void attn_mfma_kernel(
    const unsigned short* __restrict__ q, const unsigned short* __restrict__ k,
    const unsigned short* __restrict__ vt,
    float* __restrict__ Opart, float* __restrict__ lpart)
{
    constexpr int TSZ = 64 * 64;
    __shared__ __align__(16) unsigned short Ks[2 * TSZ];    // 16 KB
    __shared__ __align__(16) unsigned short Vs[2 * TSZ];    // 16 KB
    __shared__ __align__(16) unsigned short Ps[8][16 * 64]; // 16 KB, XOR-swizzled

    const int tid  = threadIdx.x;
    const int wave = tid >> 6;        // 0..7
    const int lane = tid & 63;
    const int col  = lane & 15;
    const int quad = lane >> 4;
    const int r8   = lane >> 3, cp = lane & 7;

    // XCD-locality swizzle: all 16 blocks of a bh share lin%8.
    const int lin   = (int)blockIdx.y * 16 + (int)blockIdx.x;
    const int bh    = (lin & 7) + 8 * ((lin >> 3) & 3);
    const int pairh = lin >> 5;       // 0..15
    const int pair  = pairh >> 1;     // 0..7
    const int hpar  = pairh & 1;      // key-tile parity this block owns

    const unsigned short* qb = q  + (size_t)bh * S * Dh;
    const unsigned short* kb = k  + (size_t)bh * S * Dh;
    const unsigned short* vb = vt + (size_t)bh * Dh * S;

    unsigned short* dk = &Ks[(wave * 8) * 64];
    unsigned short* dv = &Vs[(wave * 8) * 64];

    int foff[2][4];                   // K/V fragment reads, rot = local row
    #pragma unroll
    for (int ks = 0; ks < 2; ++ks)
        #pragma unroll
        for (int nt = 0; nt < 4; ++nt) {
            int r = nt * 16 + col;
            foff[ks][nt] = r * 64 + (((ks * 4 + quad) - r) & 7) * 8;
        }
    // Ps layout [row=16][key=64] shorts, 16B-chunk XOR swizzle: chunk ^= row&7
    int poffW[4][4];
    #pragma unroll
    for (int nt = 0; nt < 4; ++nt)
        #pragma unroll
        for (int reg = 0; reg < 4; ++reg) {
            int row = quad * 4 + reg;
            poffW[nt][reg] = row * 64 + (((nt * 2 + (col >> 3)) ^ (row & 7)) << 3) + (col & 7);
        }
    int poffR[2];
    #pragma unroll
    for (int ks = 0; ks < 2; ++ks)
        poffR[ks] = col * 64 + (((ks * 4 + quad) ^ (col & 7)) << 3);

    for (int phase = 0; phase < 2; ++phase) {
        const int qt  = phase ? (15 - pair) : pair;     // 128-row q-tile
        const int wr0 = qt * 128 + wave * 16;           // wave's first q-row
        const int NV  = qt + 1;                         // visits this phase

        const unsigned short *pk, *pv;
        {
            int r = wave * 8 + r8;
            pk = kb + (size_t)(hpar * 64 + r) * Dh + ((cp + r) & 7) * 8;
            pv = vb + (size_t)r * S + hpar * 64 + ((cp + r) & 7) * 8;
        }
        auto stageKV = [&](int buf) {      // stage current tile, advance 2 tiles
            gl_lds16(pk, dk + buf * TSZ);
            gl_lds16(pv, dv + buf * TSZ);
            pk += 128 * Dh;
            pv += 128;
        };

        __syncthreads();                   // protect buffers from prev phase
        stageKV(0);

        short8 qfrag[2];
        #pragma unroll
        for (int ks = 0; ks < 2; ++ks)
            qfrag[ks] = *(const short8*)(qb + (size_t)(wr0 + col) * Dh + ks * 32 + quad * 8);

        f32x4 O[4];
        float lacc[4];
        #pragma unroll
        for (int nt = 0; nt < 4; ++nt) O[nt] = (f32x4)0.f;
        #pragma unroll
        for (int r = 0; r < 4; ++r) lacc[r] = 0.f;

        auto subtile = [&](const unsigned short* Kc, const unsigned short* Vc, int t) {
            f32x4 sacc[4];
            #pragma unroll
            for (int nt = 0; nt < 4; ++nt) sacc[nt] = (f32x4)0.f;
            #pragma unroll
            for (int ks = 0; ks < 2; ++ks)
                #pragma unroll
                for (int nt = 0; nt < 4; ++nt) {
                    short8 kf = *(const short8*)&Kc[foff[ks][nt]];
                    sacc[nt] = __builtin_amdgcn_mfma_f32_16x16x32_bf16(qfrag[ks], kf, sacc[nt], 0, 0, 0);
                }
            const bool edge = (t * 64 + 63 > wr0);   // tile may exceed q-rows
            float pb[4][4];
            #pragma unroll
            for (int nt = 0; nt < 4; ++nt) {
                int key_g = t * 64 + nt * 16 + col;
                #pragma unroll
                for (int reg = 0; reg < 4; ++reg) {
                    // exp(s/8 - 8) = exp2(s * 0.125*log2e - 8*log2e)
                    float e = __builtin_amdgcn_exp2f(
                        fmaf(sacc[nt][reg], 0.18033688011112042f, -11.541560327111707f));
                    if (edge && key_g > wr0 + quad * 4 + reg) e = 0.f;
                    pb[nt][reg] = e;
                }
            }
            #pragma unroll
            for (int reg = 0; reg < 4; ++reg)
                lacc[reg] += (pb[0][reg] + pb[1][reg]) + (pb[2][reg] + pb[3][reg]);
            #pragma unroll
            for (int nt = 0; nt < 4; ++nt)
                #pragma unroll
                for (int reg = 0; reg < 4; ++reg)
                    Ps[wave][poffW[nt][reg]] = f2bf(pb[nt][reg]);
            #pragma unroll
            for (int ks = 0; ks < 2; ++ks) {
                short8 pf = *(const short8*)&Ps[wave][poffR[ks]];
                #pragma unroll
                for (int nt = 0; nt < 4; ++nt) {
                    short8 vf = *(const short8*)&Vc[foff[ks][nt]];
                    O[nt] = __builtin_amdgcn_mfma_f32_16x16x32_bf16(pf, vf, O[nt], 0, 0, 0);
                }
            }
        };

        for (int j = 0; j < NV; ++j) {
            __syncthreads();               // drains prefetch of visit j
            if (j + 1 < NV) stageKV((j + 1) & 1);
            const int t = hpar + 2 * j;    // global 64-key tile index
            if (t * 64 <= wr0 + 15)        // skip fully-masked tiles
                subtile(&Ks[(j & 1) * TSZ], &Vs[(j & 1) * TSZ], t);
        }

        #pragma unroll
        for (int reg = 0; reg < 4; ++reg) {
            float s = lacc[reg];
            #pragma unroll
            for (int off = 1; off <= 8; off <<= 1)
                s += __shfl_xor(s, off, 64);
            lacc[reg] = s;
        }

        // write unnormalized fp32 partials
        const size_t pb_base = (size_t)(hpar * 32 + bh) * S;
        #pragma unroll
        for (int reg = 0; reg < 4; ++reg) {
            int rg = wr0 + quad * 4 + reg;
            float* op = Opart + (pb_base + rg) * 64 + col;
            #pragma unroll
            for (int nt = 0; nt < 4; ++nt)
                op[nt * 16] = O[nt][reg];
            if (col == 0)
                lpart[pb_base + rg] = lacc[reg];
        }
    }
}

// ---------------------------------------------------------------------------
// Split-K combine: ctx[b][q][h*64+d] = bf16( (O0+O1) / (l0+l1) ).
// ---------------------------------------------------------------------------
__global__ __launch_bounds__(256) void combine_kernel(
    const float* __restrict__ Opart, const float* __restrict__ lpart,
    unsigned short* __restrict__ ctx)
{
    int gid = blockIdx.x * 256 + threadIdx.x;     // 32*2048*16
    int bh  = gid >> 15;
    int rem = gid & 32767;
    int qr  = rem >> 4;
    int dg  = (rem & 15) << 2;

    size_t i0 = ((size_t)bh * S + qr) * 64 + dg;
    size_t i1 = ((size_t)(32 + bh) * S + qr) * 64 + dg;
    float4 a = *(const float4*)(Opart + i0);
    float4 c = *(const float4*)(Opart + i1);
    float inv = 1.0f / (lpart[(size_t)bh * S + qr] + lpart[(size_t)(32 + bh) * S + qr]);

    int b = bh >> 4, hh = bh & 15;
    ushort4 pk;
    pk.x = f2bf((a.x + c.x) * inv);
    pk.y = f2bf((a.y + c.y) * inv);
    pk.z = f2bf((a.z + c.z) * inv);
    pk.w = f2bf((a.w + c.w) * inv);
    *(ushort4*)(ctx + ((size_t)b * S + qr) * 1024 + hh * 64 + dg) = pk;
}

// ---------------------------------------------------------------------------
extern "C" void kernel_launch(void* const* d_in, const int* in_sizes, int n_in,
                              void* d_out, int out_size, void* d_ws, size_t ws_size,
                              hipStream_t stream) {
    const float* x  = (const float*)d_in[0];
    const float* Wq = (const float*)d_in[1];
    const float* Wk = (const float*)d_in[2];
    const float* Wv = (const float*)d_in[3];
    const float* Wo = (const float*)d_in[4];
    const float* bo = (const float*)d_in[5];
    float* out = (float*)d_out;

    const size_t MK  = (size_t)M * K;        // 4M
    const size_t NK  = (size_t)N * K;        // 1M
    const size_t QKV = (size_t)Bb * H * S * Dh;

    unsigned short* xb   = (unsigned short*)d_ws;
    unsigned short* WqT  = xb  + MK;         // WqT/WkT/WvT contiguous = stacked [3072][1024]
    unsigned short* WkT  = WqT + NK;
    unsigned short* WvT  = WkT + NK;
    unsigned short* WoT  = WvT + NK;
    unsigned short* qbuf = WoT + NK;
    unsigned short* kbuf = qbuf + QKV;
    unsigned short* vtb  = kbuf + QKV;
    unsigned short* ctxb = vtb  + QKV;
    float* cosT  = (float*)(ctxb + QKV);
    float* sinT  = cosT + (size_t)S * HALF;
    float* Opart = sinT + (size_t)S * HALF;               // 2*32*2048*64 fp32
    float* lpart = Opart + (size_t)2 * 32 * S * 64;       // 2*32*2048 fp32

    // fused prep: rope tables + x->bf16 + 4x W transpose->bf16
    prep_kernel<<<5376, 256, 0, stream>>>(x, Wq, Wk, Wv, Wo,
                                          xb, WqT, WkT, WvT, WoT, cosT, sinT);

    // fused QKV projections as one stacked-N GEMM (+RoPE, +V transpose)
    // v6b: bank-conflict fix (rot=r)
    gemm_qkv_kernel<<<dim3(16, 16), 512, 0, stream>>>(
        xb, WqT, qbuf, kbuf, vtb, cosT, sinT);

    // flash attention v11: v9 structure + XCD-locality swizzle
    attn_mfma_kernel<<<dim3(16, Bb * H), 512, 0, stream>>>(qbuf, kbuf, vtb, Opart, lpart);

    // split-K combine -> bf16 ctx
    combine_kernel<<<4096, 256, 0, stream>>>(Opart, lpart, ctxb);

    // output projection: 64x64 tiles, BK=64, 1024 blocks = 4/CU
    gemm_out_kernel<<<dim3(16, 64), 256, 0, stream>>>(ctxb, WoT, out, bo);
}